// Round 8
// baseline (260.997 us; speedup 1.0000x reference)
//
#include <hip/hip_runtime.h>

// NCC forces, 192^3 fp32. Round 8: wave-autonomous rewrite — ZERO LDS, ZERO
// barriers. (R4-R7 showed the 2-barrier LDS skeleton plateaus at ~83 us:
// barrier-serialized critical path, not any single pipe.)
//  - wave (64 lanes) owns: x-tile 60 out cols (lanes = x incl +/-2 halo) x
//    4 out rows x 12-slice z-seg. 3072 waves = 768 blocks x 4.
//  - per-thread running z-sums (5 fields x 8 rows) updated add/sub; the z-5
//    subtract re-reads from global (L2 hit: same wave touched it 5 iters ago).
//  - 4-deep per-thread raw ring (6 rows) for x/y/z gradients.
//  - x-box and x-gradient via DPP wave_shr:1/wave_shl:1 (dir verified R7:
//    shr = lane i <- i-1). bound_ctrl=1 zeros spill lanes; halo lanes cover
//    tile seams; zero-pad = conv SAME semantics.
//  - loads for next slice issue BEFORE the emit block (~400 indep VALU cover).
//  - XCD swizzle: each XCD owns 2 contiguous z-segs (all y-groups).

#define DD 192
#define HH 192
#define WW 192
#define NVOX (DD * HH * WW)
#define ZS 12            // z-slices per wave
#define NZS 16           // 192/12 z-segments
#define YG 48            // y-groups (4 out rows each)
#define ROWS 8           // sum rows: y0-2 .. y0+5
#define RING 6           // ring rows: y0-1 .. y0+4

__device__ __forceinline__ float wsr1(float v) {   // lane i <- lane i-1 (x-1); lane0 <- 0
    return __int_as_float(__builtin_amdgcn_update_dpp(0, __float_as_int(v), 0x138, 0xF, 0xF, true));
}
__device__ __forceinline__ float wsl1(float v) {   // lane i <- lane i+1 (x+1); lane63 <- 0
    return __int_as_float(__builtin_amdgcn_update_dpp(0, __float_as_int(v), 0x130, 0xF, 0xF, true));
}

__global__ __launch_bounds__(256, 3)
void ncc_forces_kernel(const float* __restrict__ mimg,
                       const float* __restrict__ fimg,
                       const int*   __restrict__ mmask,
                       const int*   __restrict__ fmask,
                       float* __restrict__ out)
{
    // 768 blocks; swizzle so XCD k gets logical blocks [k*96,(k+1)*96) =
    // z-segs {2k,2k+1} x all 48 y-groups.
    const int b  = blockIdx.x;
    const int L  = (b & 7) * 96 + (b >> 3);
    const int zs = L / YG;
    const int yg = L - zs * YG;
    const int w    = threadIdx.x >> 6;       // wave 0..3 = x-tile
    const int lane = threadIdx.x & 63;

    const int x0 = w * 60;
    const int gx = x0 + lane - 2;            // -2 .. 241
    const int y0 = yg * 4;
    const int zstart = zs * ZS;
    const bool gxok = (gx >= 0) && (gx < WW);
    const bool emitlane = (lane >= 2) && (lane < 62) && (gx < WW);

    float sums[ROWS][5];
#pragma unroll
    for (int r = 0; r < ROWS; ++r)
#pragma unroll
        for (int f = 0; f < 5; ++f) sums[r][f] = 0.f;
    float rm[RING][4], rf[RING][4];
#pragma unroll
    for (int rr = 0; rr < RING; ++rr)
#pragma unroll
        for (int k = 0; k < 4; ++k) { rm[rr][k] = 0.f; rf[rr][k] = 0.f; }

    for (int n = 0; n <= ZS + 4; ++n) {
        const int zl = zstart - 2 + n;       // slice loaded/added this iter
        const int zo = zl - 5;               // slice subtracted this iter
        const int z_out = zstart + n - 5;    // slice emitted this iter
        const bool doload = (n < ZS + 4);    // last iter only emits
        const bool dosub  = doload && (n >= 5);
        const bool emitv  = (n >= 5);

        // ---- step 1: issue loads (fresh zl, old zo, masks for z_out) ----
        float fm[ROWS], fff[ROWS], om[ROWS], off[ROWS];
#pragma unroll
        for (int r = 0; r < ROWS; ++r) {
            const int gy = y0 - 2 + r;
            const bool yok = (gy >= 0) && (gy < HH) && gxok;
            const bool fok = doload && yok && (zl >= 0) && (zl < DD);
            const bool ook = dosub  && yok && (zo >= 0) && (zo < DD);
            const size_t fi = ((size_t)zl * HH + gy) * WW + gx;
            const size_t oi = ((size_t)zo * HH + gy) * WW + gx;
            fm[r]  = fok ? mimg[fi] : 0.f;
            fff[r] = fok ? fimg[fi] : 0.f;
            om[r]  = ook ? mimg[oi] : 0.f;
            off[r] = ook ? fimg[oi] : 0.f;
        }
        int um[4], uf[4];
#pragma unroll
        for (int j = 0; j < 4; ++j) { um[j] = 0; uf[j] = 0; }
        if (emitv && emitlane) {
#pragma unroll
            for (int j = 0; j < 4; ++j) {
                const int vidx = (z_out * HH + (y0 + j)) * WW + gx;
                um[j] = __builtin_nontemporal_load(mmask + vidx);
                uf[j] = __builtin_nontemporal_load(fmask + vidx);
            }
        }

        // ---- step 2: emit z_out (independent of step-1 loads) ----
        // sums are complete through zl-1 = z_out+2; ring slot k holds
        // slice (zstart+n-3-k): slot1=z_out+1, slot2=z_out, slot3=z_out-1.
        if (emitv) {
#pragma unroll
            for (int j = 0; j < 4; ++j) {
                const int gy = y0 + j;
                float box[5];
#pragma unroll
                for (int f = 0; f < 5; ++f) {
                    const float s = sums[j][f] + sums[j + 1][f] + sums[j + 2][f]
                                  + sums[j + 3][f] + sums[j + 4][f];
                    const float t1 = wsr1(s), t2 = wsr1(t1);
                    const float u1 = wsl1(s), u2 = wsl1(u1);
                    box[f] = s + t1 + t2 + u1 + u2;
                }
                const float mc = rm[j + 1][2], fc = rf[j + 1][2];

                // gradients (jnp.gradient: central interior, one-sided edges)
                const float mxm = wsr1(mc), mxp = wsl1(mc);
                const float fxm = wsr1(fc), fxp = wsl1(fc);
                float gxm_, gxf_, gym_, gyf_, gzm_, gzf_;
                if (gx == 0)           { gxm_ = mxp - mc;  gxf_ = fxp - fc; }
                else if (gx == WW - 1) { gxm_ = mc - mxm;  gxf_ = fc - fxm; }
                else                   { gxm_ = 0.5f * (mxp - mxm); gxf_ = 0.5f * (fxp - fxm); }

                if (gy == 0)           { gym_ = rm[j + 2][2] - mc;  gyf_ = rf[j + 2][2] - fc; }
                else if (gy == HH - 1) { gym_ = mc - rm[j][2];      gyf_ = fc - rf[j][2]; }
                else { gym_ = 0.5f * (rm[j + 2][2] - rm[j][2]); gyf_ = 0.5f * (rf[j + 2][2] - rf[j][2]); }

                if (z_out == 0)           { gzm_ = rm[j + 1][1] - mc;  gzf_ = rf[j + 1][1] - fc; }
                else if (z_out == DD - 1) { gzm_ = mc - rm[j + 1][3];  gzf_ = fc - rf[j + 1][3]; }
                else { gzm_ = 0.5f * (rm[j + 1][1] - rm[j + 1][3]); gzf_ = 0.5f * (rf[j + 1][1] - rf[j + 1][3]); }

                const float u = ((um[j] | uf[j]) != 0) ? 1.0f : 0.0f;

                const float npix = 125.0f;
                const float inv_npix = 1.0f / 125.0f;
                const float mean_m = box[0] * inv_npix;
                const float mean_f = box[1] * inv_npix;
                const float var_m = box[2] - 2.0f * mean_m * box[0] + npix * mean_m * mean_m;
                const float var_f = box[3] - 2.0f * mean_f * box[1] + npix * mean_f * mean_f;
                const float var_mf = var_m * var_f;
                const float cross = box[4] - mean_f * box[0] - mean_m * box[1]
                                  + npix * mean_m * mean_f;
                const float mmc = mc - mean_m;
                const float fmc = fc - mean_f;
                const bool ok = (var_mf > 1e-5f) && (var_f > 1e-5f) && (fmc != 0.0f) && (mmc != 0.0f);
                float factor = 0.0f;
                if (ok) factor = 2.0f * cross / var_mf * (mmc - cross * fmc / var_f);

                if (emitlane) {
                    const int vidx = (z_out * HH + gy) * WW + gx;
                    const float nf = -factor * 0.5f * u;
                    out[vidx]            = nf * (gzm_ + gzf_);   // ch 0: d/dD
                    out[NVOX + vidx]     = nf * (gym_ + gyf_);   // ch 1: d/dH
                    out[2 * NVOX + vidx] = nf * (gxm_ + gxf_);   // ch 2: d/dW
                }
            }
        }

        // ---- step 3: consume loads — update sums, shift rings ----
        if (doload) {
#pragma unroll
            for (int r = 0; r < ROWS; ++r) {
                sums[r][0] += fm[r] - om[r];
                sums[r][1] += fff[r] - off[r];
                sums[r][2] += fm[r] * fm[r]  - om[r] * om[r];
                sums[r][3] += fff[r] * fff[r] - off[r] * off[r];
                sums[r][4] += fm[r] * fff[r] - om[r] * off[r];
            }
#pragma unroll
            for (int rr = 0; rr < RING; ++rr) {
                rm[rr][3] = rm[rr][2]; rm[rr][2] = rm[rr][1]; rm[rr][1] = rm[rr][0];
                rm[rr][0] = fm[rr + 1];
                rf[rr][3] = rf[rr][2]; rf[rr][2] = rf[rr][1]; rf[rr][1] = rf[rr][0];
                rf[rr][0] = fff[rr + 1];
            }
        }
    }
}

extern "C" void kernel_launch(void* const* d_in, const int* in_sizes, int n_in,
                              void* d_out, int out_size, void* d_ws, size_t ws_size,
                              hipStream_t stream)
{
    const float* mimg  = (const float*)d_in[0];
    const float* fimg  = (const float*)d_in[1];
    const int*   mmask = (const int*)d_in[2];
    const int*   fmask = (const int*)d_in[3];
    float* out = (float*)d_out;

    dim3 grid(8 * 96, 1, 1);    // 768 blocks x 4 waves = 3072 wave-units
    dim3 block(256, 1, 1);
    hipLaunchKernelGGL(ncc_forces_kernel, grid, block, 0, stream,
                       mimg, fimg, mmask, fmask, out);
}